// Round 5
// baseline (254.645 us; speedup 1.0000x reference)
//
#include <hip/hip_runtime.h>
#include <hip/hip_bf16.h>
#include <math.h>

#define F_IN 300
#define HDIM 128
#define HO   256   // combined Wl|Wr output dim
#define KP   320   // K padded to 10 x 32
#define NKS  10
#define CLS  2
#define MB   64    // node rows per proj tile
#define NPB  64    // nodes per gather/pool block
#define CHUNK 1024 // scan chunk (256 threads x 4)
#define PROJ_BLOCKS 512

typedef short short8 __attribute__((ext_vector_type(8)));
typedef float f32x4 __attribute__((ext_vector_type(4)));

static __device__ __forceinline__ unsigned short f2bf(float f) {
    union { float f; unsigned int u; } v; v.f = f;
    unsigned int u = v.u;
    unsigned int r = (u + 0x7FFFu + ((u >> 16) & 1u)) >> 16;   // RNE
    return (unsigned short)r;
}
static __device__ __forceinline__ float bf2f(unsigned short h) {
    union { unsigned int u; float f; } v; v.u = ((unsigned int)h) << 16;
    return v.f;
}

// Pack W fragments: Wb[((ks*16+ct)*4+hi)*16+c15][j] bf16, k=ks*32+hi*8+j, c=ct*16+c15
__global__ __launch_bounds__(256) void prepw_kernel(const float* __restrict__ Wl,
                                                    const float* __restrict__ Wr,
                                                    unsigned short* __restrict__ Wb) {
    int i = blockIdx.x * 256 + threadIdx.x;
    if (i >= KP * HO) return;
    int j   = i & 7;
    int c15 = (i >> 3) & 15;
    int hi  = (i >> 7) & 3;
    int ctk = i >> 9;
    int ct  = ctk & 15;
    int ks  = ctk >> 4;
    int k = ks * 32 + hi * 8 + j;
    int c = ct * 16 + c15;
    float v = 0.f;
    if (k < F_IN) v = (c < HDIM) ? Wl[c * F_IN + k] : Wr[(c - HDIM) * F_IN + k];
    Wb[i] = f2bf(v);
}

// Pipelined persistent-W MFMA projection.
// Per tile: issue next tile's global loads -> MFMA current LDS buffer ->
// epilogue -> convert+write next buffer -> barrier. One barrier/tile.
__global__ __launch_bounds__(512) void proj_kernel(const float* __restrict__ x,
                                                   const unsigned short* __restrict__ Wb,
                                                   unsigned short* __restrict__ xPb,
                                                   int N, int ntiles) {
    __shared__ unsigned short xs[2][MB * KP];   // 2 x 40 KB, swizzled
    int tid = threadIdx.x;
    int lane = tid & 63, w = tid >> 6;          // wave w owns channels 32w..32w+31
    int lo = lane & 15, hi = lane >> 4;

    // ---- W prologue: 20 fragments resident (A-operand role) ----
    short8 wfrag[NKS][2];
#pragma unroll
    for (int ks = 0; ks < NKS; ++ks)
#pragma unroll
        for (int c = 0; c < 2; ++c) {
            int ct = 2 * w + c;
            wfrag[ks][c] = *reinterpret_cast<const short8*>(
                Wb + (size_t)(ks * 16 + ct) * 512 + hi * 128 + lo * 8);
        }

    // staging index map for this thread: idx = tid + 512*it, row=idx/40, g=idx%40
    int srow[5], sg[5];
#pragma unroll
    for (int it = 0; it < 5; ++it) {
        int idx = tid + it * 512;
        srow[it] = idx / 40;
        sg[it]   = idx - srow[it] * 40;
    }

    float4 pre[5][2];

    // ---- load tile t's X slice into registers (no wait) ----
    auto stage_load = [&](int tile) {
        int n0 = tile * MB;
#pragma unroll
        for (int it = 0; it < 5; ++it) {
            int k0 = sg[it] * 8;
            int gr = n0 + srow[it];
            float4 z = {0.f, 0.f, 0.f, 0.f};
            pre[it][0] = z; pre[it][1] = z;
            if (gr < N) {
                const float* xr = x + (size_t)gr * F_IN;
                if (k0 + 8 <= F_IN) {
                    pre[it][0] = *reinterpret_cast<const float4*>(xr + k0);
                    pre[it][1] = *reinterpret_cast<const float4*>(xr + k0 + 4);
                } else if (k0 < F_IN) {
                    // k0=296: 4 valid floats
                    pre[it][0] = *reinterpret_cast<const float4*>(xr + k0);
                }
            }
        }
    };

    // ---- convert + write staged regs into LDS buffer b ----
    auto stage_write = [&](char* xsb) {
#pragma unroll
        for (int it = 0; it < 5; ++it) {
            int g = sg[it], row = srow[it];
            unsigned short tmp[8];
            tmp[0] = f2bf(pre[it][0].x); tmp[1] = f2bf(pre[it][0].y);
            tmp[2] = f2bf(pre[it][0].z); tmp[3] = f2bf(pre[it][0].w);
            tmp[4] = f2bf(pre[it][1].x); tmp[5] = f2bf(pre[it][1].y);
            tmp[6] = f2bf(pre[it][1].z); tmp[7] = f2bf(pre[it][1].w);
            int boff = g * 1024 + ((row ^ (g & 7)) << 4);
            *reinterpret_cast<short8*>(xsb + boff) = *reinterpret_cast<const short8*>(tmp);
        }
    };

    int tile = blockIdx.x;
    if (tile >= ntiles) return;

    stage_load(tile);
    stage_write((char*)xs[0]);
    __syncthreads();

    int p = 0;
    while (tile < ntiles) {
        int nxt = tile + gridDim.x;
        if (nxt < ntiles) stage_load(nxt);     // in flight during MFMA

        char* xsb = (char*)xs[p];
        f32x4 acc[4][2];
#pragma unroll
        for (int r = 0; r < 4; ++r) {
            acc[r][0] = (f32x4){0.f, 0.f, 0.f, 0.f};
            acc[r][1] = (f32x4){0.f, 0.f, 0.f, 0.f};
        }
#pragma unroll
        for (int ks = 0; ks < NKS; ++ks) {
            int g = ks * 4 + hi;
            int lob = g * 1024 + ((lo ^ (g & 7)) << 4);
#pragma unroll
            for (int r = 0; r < 4; ++r) {
                short8 a = *reinterpret_cast<const short8*>(xsb + lob + r * 256);
                // swapped operands: D rows = channels, D cols = X rows
                acc[r][0] = __builtin_amdgcn_mfma_f32_16x16x32_bf16(wfrag[ks][0], a, acc[r][0], 0, 0, 0);
                acc[r][1] = __builtin_amdgcn_mfma_f32_16x16x32_bf16(wfrag[ks][1], a, acc[r][1], 0, 0, 0);
            }
        }

        // ---- epilogue: X row = n0 + r*16 + lo; channels (2w+c)*16 + hi*4 + rr ----
        int n0 = tile * MB;
#pragma unroll
        for (int r = 0; r < 4; ++r) {
            int row = n0 + r * 16 + lo;
            if (row < N) {
#pragma unroll
                for (int c = 0; c < 2; ++c) {
                    unsigned short pk[4];
                    pk[0] = f2bf(acc[r][c][0]); pk[1] = f2bf(acc[r][c][1]);
                    pk[2] = f2bf(acc[r][c][2]); pk[3] = f2bf(acc[r][c][3]);
                    *reinterpret_cast<uint2*>(xPb + (size_t)row * HO + (2 * w + c) * 16 + hi * 4) =
                        *reinterpret_cast<const uint2*>(pk);
                }
            }
        }

        if (nxt < ntiles) stage_write((char*)xs[p ^ 1]);
        __syncthreads();
        p ^= 1;
        tile = nxt;
    }
}

// ---- CSR build ----
__global__ __launch_bounds__(256) void count_kernel(const int* __restrict__ ei,
                                                    int* __restrict__ cnt, int E) {
    int e = blockIdx.x * 256 + threadIdx.x;
    if (e >= E) return;
    atomicAdd(&cnt[ei[E + e]], 1);   // dst
}

__global__ __launch_bounds__(256) void scan1_kernel(const int* __restrict__ cnt,
                                                    int* __restrict__ tmp,
                                                    int* __restrict__ bsum, int N) {
    __shared__ int ssum[256];
    int t = threadIdx.x;
    int base = blockIdx.x * CHUNK + t * 4;
    int c[4];
#pragma unroll
    for (int j = 0; j < 4; ++j) c[j] = (base + j < N) ? cnt[base + j] : 0;
    int s = c[0] + c[1] + c[2] + c[3];
    ssum[t] = s;
    __syncthreads();
    for (int off = 1; off < 256; off <<= 1) {
        int a = (t >= off) ? ssum[t - off] : 0;
        __syncthreads();
        ssum[t] += a;
        __syncthreads();
    }
    int run = ssum[t] - s;
#pragma unroll
    for (int j = 0; j < 4; ++j) {
        if (base + j < N) tmp[base + j] = run;
        run += c[j];
    }
    if (t == 255) bsum[blockIdx.x] = ssum[255];
}

__global__ __launch_bounds__(256) void scan2_kernel(int* __restrict__ bsum, int nb) {
    __shared__ int sd[256];
    int t = threadIdx.x;
    int v = (t < nb) ? bsum[t] : 0;
    sd[t] = v;
    __syncthreads();
    for (int off = 1; off < 256; off <<= 1) {
        int a = (t >= off) ? sd[t - off] : 0;
        __syncthreads();
        sd[t] += a;
        __syncthreads();
    }
    if (t < nb) bsum[t] = sd[t] - v;
}

__global__ __launch_bounds__(256) void scan3_kernel(const int* __restrict__ tmp,
                                                    const int* __restrict__ bsum,
                                                    int* __restrict__ rowptr,
                                                    int* __restrict__ cursor, int N) {
    int i = blockIdx.x * 256 + threadIdx.x;
    if (i >= N) return;
    int v = tmp[i] + bsum[i >> 10];
    rowptr[i] = v;
    cursor[i] = v;
}

__global__ __launch_bounds__(256) void fill_kernel(const int* __restrict__ ei,
                                                   int* __restrict__ cursor,
                                                   int* __restrict__ srcl, int E) {
    int e = blockIdx.x * 256 + threadIdx.x;
    if (e >= E) return;
    int s = ei[e];
    int d = ei[E + e];
    int pos = atomicAdd(&cursor[d], 1);
    srcl[pos] = s;
}

// gather mean + h = relu(mean + bl + xWr) + global_max_pool (batch sorted)
__global__ __launch_bounds__(128) void gather_pool_kernel(const unsigned short* __restrict__ xPb,
                                                          const int* __restrict__ rowptr,
                                                          const int* __restrict__ rowend,
                                                          const int* __restrict__ srcl,
                                                          const float* __restrict__ bl,
                                                          const int* __restrict__ batch,
                                                          float* __restrict__ gpool, int N) {
    int t = threadIdx.x;
    int n0 = blockIdx.x * NPB;
    if (n0 >= N) return;
    float blv = bl[t];
    float runmax = 0.f;
    int curg = batch[n0];
    int nmax = N - n0; if (nmax > NPB) nmax = NPB;
    for (int i = 0; i < nmax; ++i) {
        int n = n0 + i;
        int gb = batch[n];
        if (gb != curg) {
            atomicMax((unsigned int*)&gpool[curg * HDIM + t], __float_as_uint(runmax));
            runmax = 0.f;
            curg = gb;
        }
        int e0 = rowptr[n];
        int e1 = rowend[n];
        float acc = 0.f;
        for (int e = e0; e < e1; ++e) {
            int s = srcl[e];
            acc += bf2f(xPb[(size_t)s * HO + t]);
        }
        float rv = 1.0f / fmaxf((float)(e1 - e0), 1.0f);
        float h = fmaf(acc, rv, blv + bf2f(xPb[(size_t)n * HO + HDIM + t]));
        h = fmaxf(h, 0.f);
        runmax = fmaxf(runmax, h);
    }
    atomicMax((unsigned int*)&gpool[curg * HDIM + t], __float_as_uint(runmax));
}

__global__ __launch_bounds__(256) void root_kernel(const int* __restrict__ batch,
                                                   int* __restrict__ root, int N) {
    int i = blockIdx.x * 256 + threadIdx.x;
    if (i >= N) return;
    if (i == 0 || batch[i] != batch[i - 1]) root[batch[i]] = i;
}

__global__ __launch_bounds__(128) void final_kernel(const float* __restrict__ x,
                                                    const int* __restrict__ root,
                                                    const float* __restrict__ gpool,
                                                    const float* __restrict__ W0,
                                                    const float* __restrict__ b0,
                                                    const float* __restrict__ W1,
                                                    const float* __restrict__ b1,
                                                    const float* __restrict__ W2,
                                                    const float* __restrict__ b2,
                                                    float* __restrict__ out) {
    __shared__ float xrow[F_IN];
    __shared__ float cat[HO];
    __shared__ float h1s[HDIM];
    __shared__ float part[2][2];
    int g = blockIdx.x, t = threadIdx.x;
    int r = root[g];
    const float* xr = x + (size_t)r * F_IN;
    for (int k = t; k < F_IN; k += HDIM) xrow[k] = xr[k];
    __syncthreads();

    float a = b0[t];
    const float* w0r = W0 + t * F_IN;
    for (int k = 0; k < F_IN; ++k) a = fmaf(xrow[k], w0r[k], a);
    cat[t] = fmaxf(a, 0.f);
    cat[HDIM + t] = gpool[g * HDIM + t];
    __syncthreads();

    float s = b1[t];
    const float* w1r = W1 + t * HO;
    for (int k = 0; k < HO; ++k) s = fmaf(cat[k], w1r[k], s);
    h1s[t] = fmaxf(s, 0.f);
    __syncthreads();

    float hv = h1s[t];
    float p0 = hv * W2[t];
    float p1 = hv * W2[HDIM + t];
#pragma unroll
    for (int o2 = 32; o2 > 0; o2 >>= 1) {
        p0 += __shfl_down(p0, o2);
        p1 += __shfl_down(p1, o2);
    }
    int lane = t & 63, wv = t >> 6;
    if (lane == 0) { part[0][wv] = p0; part[1][wv] = p1; }
    __syncthreads();
    if (t == 0) {
        float z0 = part[0][0] + part[0][1] + b2[0];
        float z1 = part[1][0] + part[1][1] + b2[1];
        float m = fmaxf(z0, z1);
        float lse = m + logf(expf(z0 - m) + expf(z1 - m));
        out[g * CLS + 0] = z0 - lse;
        out[g * CLS + 1] = z1 - lse;
    }
}

extern "C" void kernel_launch(void* const* d_in, const int* in_sizes, int n_in,
                              void* d_out, int out_size, void* d_ws, size_t ws_size,
                              hipStream_t stream) {
    const float* x     = (const float*)d_in[0];
    const int*   ei    = (const int*)d_in[1];
    const int*   batch = (const int*)d_in[2];
    const float* Wl    = (const float*)d_in[3];
    const float* bl    = (const float*)d_in[4];
    const float* Wr    = (const float*)d_in[5];
    const float* W0    = (const float*)d_in[6];
    const float* b0    = (const float*)d_in[7];
    const float* W1    = (const float*)d_in[8];
    const float* b1    = (const float*)d_in[9];
    const float* W2    = (const float*)d_in[10];
    const float* b2    = (const float*)d_in[11];
    float* out = (float*)d_out;

    int N = in_sizes[2];
    int E = in_sizes[1] / 2;
    int G = out_size / CLS;

    char* ws = (char*)d_ws;
    size_t off = 0;
    auto carve = [&](size_t bytes) -> void* {
        void* p = ws + off;
        off += (bytes + 255) & ~(size_t)255;
        return p;
    };
    unsigned short* xPb = (unsigned short*)carve((size_t)N * HO * sizeof(unsigned short));
    char*  zbeg   = ws + off;
    int*   cnt    = (int*)carve((size_t)N * sizeof(int));
    float* gpool  = (float*)carve((size_t)G * HDIM * sizeof(float));
    char*  zend   = ws + off;
    int*   tmp    = (int*)carve((size_t)N * sizeof(int));
    int*   rowptr = (int*)carve((size_t)N * sizeof(int));
    int*   cursor = (int*)carve((size_t)N * sizeof(int));
    int*   srcl   = (int*)carve((size_t)E * sizeof(int));
    int*   bsum   = (int*)carve(1024 * sizeof(int));
    unsigned short* Wb = (unsigned short*)carve((size_t)KP * HO * sizeof(unsigned short));
    int*   root   = (int*)carve((size_t)G * sizeof(int));
    (void)ws_size; (void)n_in;

    int nb = (N + CHUNK - 1) / CHUNK;
    int ntiles = (N + MB - 1) / MB;
    int pblocks = ntiles < PROJ_BLOCKS ? ntiles : PROJ_BLOCKS;

    hipMemsetAsync(zbeg, 0, (size_t)(zend - zbeg), stream);

    prepw_kernel<<<(KP * HO + 255) / 256, 256, 0, stream>>>(Wl, Wr, Wb);
    proj_kernel<<<pblocks, 512, 0, stream>>>(x, Wb, xPb, N, ntiles);

    count_kernel<<<(E + 255) / 256, 256, 0, stream>>>(ei, cnt, E);
    scan1_kernel<<<nb, 256, 0, stream>>>(cnt, tmp, bsum, N);
    scan2_kernel<<<1, 256, 0, stream>>>(bsum, nb);
    scan3_kernel<<<(N + 255) / 256, 256, 0, stream>>>(tmp, bsum, rowptr, cursor, N);
    fill_kernel<<<(E + 255) / 256, 256, 0, stream>>>(ei, cursor, srcl, E);

    gather_pool_kernel<<<(N + NPB - 1) / NPB, HDIM, 0, stream>>>(xPb, rowptr, cursor, srcl,
                                                                 bl, batch, gpool, N);
    root_kernel<<<(N + 255) / 256, 256, 0, stream>>>(batch, root, N);
    final_kernel<<<G, HDIM, 0, stream>>>(x, root, gpool, W0, b0, W1, b1, W2, b2, out);
}

// Round 6
// 249.325 us; speedup vs baseline: 1.0213x; 1.0213x over previous
//
#include <hip/hip_runtime.h>
#include <hip/hip_bf16.h>
#include <math.h>

#define F_IN 300
#define HDIM 128
#define HO   256   // combined Wl|Wr output dim
#define KP   320   // K padded to 10 x 32
#define NKS  10
#define CLS  2
#define MB   64    // node rows per proj tile
#define NPB  64    // nodes per gather/pool block
#define CHUNK 1024 // scan chunk (256 threads x 4)
#define PROJ_BLOCKS 512
#define CSTRIDE 528  // cbuf row stride bytes (512 + 16 pad)

typedef short short8 __attribute__((ext_vector_type(8)));
typedef float f32x4 __attribute__((ext_vector_type(4)));

static __device__ __forceinline__ unsigned short f2bf(float f) {
    union { float f; unsigned int u; } v; v.f = f;
    unsigned int u = v.u;
    unsigned int r = (u + 0x7FFFu + ((u >> 16) & 1u)) >> 16;   // RNE
    return (unsigned short)r;
}
static __device__ __forceinline__ float bf2f(unsigned short h) {
    union { unsigned int u; float f; } v; v.u = ((unsigned int)h) << 16;
    return v.f;
}

// Pack W fragments: Wb[((ks*16+ct)*4+hi)*16+c15][j] bf16, k=ks*32+hi*8+j, c=ct*16+c15
__global__ __launch_bounds__(256) void prepw_kernel(const float* __restrict__ Wl,
                                                    const float* __restrict__ Wr,
                                                    unsigned short* __restrict__ Wb) {
    int i = blockIdx.x * 256 + threadIdx.x;
    if (i >= KP * HO) return;
    int j   = i & 7;
    int c15 = (i >> 3) & 15;
    int hi  = (i >> 7) & 3;
    int ctk = i >> 9;
    int ct  = ctk & 15;
    int ks  = ctk >> 4;
    int k = ks * 32 + hi * 8 + j;
    int c = ct * 16 + c15;
    float v = 0.f;
    if (k < F_IN) v = (c < HDIM) ? Wl[c * F_IN + k] : Wr[(c - HDIM) * F_IN + k];
    Wb[i] = f2bf(v);
}

// Pipelined persistent-W MFMA projection with LDS-transposed coalesced epilogue.
__global__ __launch_bounds__(512) void proj_kernel(const float* __restrict__ x,
                                                   const unsigned short* __restrict__ Wb,
                                                   unsigned short* __restrict__ xPb,
                                                   int N, int ntiles) {
    __shared__ unsigned short xs[MB * KP];      // 40 KB X tile, swizzled
    __shared__ char cbuf[MB * CSTRIDE];         // 33 KB C transpose buffer
    int tid = threadIdx.x;
    int lane = tid & 63, w = tid >> 6;          // wave w owns channels 32w..32w+31
    int lo = lane & 15, hi = lane >> 4;

    // ---- W prologue: 20 fragments resident (A-operand role) ----
    short8 wfrag[NKS][2];
#pragma unroll
    for (int ks = 0; ks < NKS; ++ks)
#pragma unroll
        for (int c = 0; c < 2; ++c) {
            int ct = 2 * w + c;
            wfrag[ks][c] = *reinterpret_cast<const short8*>(
                Wb + (size_t)(ks * 16 + ct) * 512 + hi * 128 + lo * 8);
        }

    int srow[5], sg[5];
#pragma unroll
    for (int it = 0; it < 5; ++it) {
        int idx = tid + it * 512;
        srow[it] = idx / 40;
        sg[it]   = idx - srow[it] * 40;
    }

    float4 pre[5][2];

    auto stage_load = [&](int tile) {
        int n0 = tile * MB;
#pragma unroll
        for (int it = 0; it < 5; ++it) {
            int k0 = sg[it] * 8;
            int gr = n0 + srow[it];
            float4 z = {0.f, 0.f, 0.f, 0.f};
            pre[it][0] = z; pre[it][1] = z;
            if (gr < N) {
                const float* xr = x + (size_t)gr * F_IN;
                if (k0 + 8 <= F_IN) {
                    pre[it][0] = *reinterpret_cast<const float4*>(xr + k0);
                    pre[it][1] = *reinterpret_cast<const float4*>(xr + k0 + 4);
                } else if (k0 < F_IN) {
                    pre[it][0] = *reinterpret_cast<const float4*>(xr + k0);
                }
            }
        }
    };

    auto stage_write = [&](char* xsb) {
#pragma unroll
        for (int it = 0; it < 5; ++it) {
            int g = sg[it], row = srow[it];
            unsigned short tmp[8];
            tmp[0] = f2bf(pre[it][0].x); tmp[1] = f2bf(pre[it][0].y);
            tmp[2] = f2bf(pre[it][0].z); tmp[3] = f2bf(pre[it][0].w);
            tmp[4] = f2bf(pre[it][1].x); tmp[5] = f2bf(pre[it][1].y);
            tmp[6] = f2bf(pre[it][1].z); tmp[7] = f2bf(pre[it][1].w);
            int boff = g * 1024 + ((row ^ (g & 7)) << 4);
            *reinterpret_cast<short8*>(xsb + boff) = *reinterpret_cast<const short8*>(tmp);
        }
    };

    int tile = blockIdx.x;
    if (tile >= ntiles) return;

    stage_load(tile);
    stage_write((char*)xs);
    __syncthreads();

    while (tile < ntiles) {
        int nxt = tile + gridDim.x;
        if (nxt < ntiles) stage_load(nxt);     // HBM loads in flight during MFMA

        char* xsb = (char*)xs;
        f32x4 acc[4][2];
#pragma unroll
        for (int r = 0; r < 4; ++r) {
            acc[r][0] = (f32x4){0.f, 0.f, 0.f, 0.f};
            acc[r][1] = (f32x4){0.f, 0.f, 0.f, 0.f};
        }
#pragma unroll
        for (int ks = 0; ks < NKS; ++ks) {
            int g = ks * 4 + hi;
            int lob = g * 1024 + ((lo ^ (g & 7)) << 4);
#pragma unroll
            for (int r = 0; r < 4; ++r) {
                short8 a = *reinterpret_cast<const short8*>(xsb + lob + r * 256);
                // swapped operands: D rows = channels, D cols = X rows
                acc[r][0] = __builtin_amdgcn_mfma_f32_16x16x32_bf16(wfrag[ks][0], a, acc[r][0], 0, 0, 0);
                acc[r][1] = __builtin_amdgcn_mfma_f32_16x16x32_bf16(wfrag[ks][1], a, acc[r][1], 0, 0, 0);
            }
        }

        // ---- epilogue stage 1: C fragments -> cbuf (transpose in LDS) ----
        // thread's fragment: local row = r*16+lo, channels (2w+c)*16 + hi*4 + [0..3]
#pragma unroll
        for (int r = 0; r < 4; ++r) {
#pragma unroll
            for (int c = 0; c < 2; ++c) {
                unsigned short pk[4];
                pk[0] = f2bf(acc[r][c][0]); pk[1] = f2bf(acc[r][c][1]);
                pk[2] = f2bf(acc[r][c][2]); pk[3] = f2bf(acc[r][c][3]);
                int row = r * 16 + lo;
                int ch  = (2 * w + c) * 16 + hi * 4;
                *reinterpret_cast<uint2*>(cbuf + row * CSTRIDE + ch * 2) =
                    *reinterpret_cast<const uint2*>(pk);
            }
        }
        __syncthreads();   // MFMA reads of xs done by all waves; cbuf complete

        // ---- epilogue stage 2: coalesced row stores (512B/wave/instr) ----
        int n0 = tile * MB;
#pragma unroll
        for (int i = 0; i < 8; ++i) {
            int row = i * 8 + w;
            int gr = n0 + row;
            uint2 v = *reinterpret_cast<const uint2*>(cbuf + row * CSTRIDE + lane * 8);
            if (gr < N)
                *reinterpret_cast<uint2*>(xPb + (size_t)gr * HO + lane * 4) = v;
        }

        if (nxt < ntiles) stage_write((char*)xs);   // xs free: all MFMA reads done
        __syncthreads();
        tile = nxt;
    }
}

// ---- CSR build ----
__global__ __launch_bounds__(256) void count_kernel(const int* __restrict__ ei,
                                                    int* __restrict__ cnt, int E) {
    int e = blockIdx.x * 256 + threadIdx.x;
    if (e >= E) return;
    atomicAdd(&cnt[ei[E + e]], 1);   // dst
}

__global__ __launch_bounds__(256) void scan1_kernel(const int* __restrict__ cnt,
                                                    int* __restrict__ tmp,
                                                    int* __restrict__ bsum, int N) {
    __shared__ int ssum[256];
    int t = threadIdx.x;
    int base = blockIdx.x * CHUNK + t * 4;
    int c[4];
#pragma unroll
    for (int j = 0; j < 4; ++j) c[j] = (base + j < N) ? cnt[base + j] : 0;
    int s = c[0] + c[1] + c[2] + c[3];
    ssum[t] = s;
    __syncthreads();
    for (int off = 1; off < 256; off <<= 1) {
        int a = (t >= off) ? ssum[t - off] : 0;
        __syncthreads();
        ssum[t] += a;
        __syncthreads();
    }
    int run = ssum[t] - s;
#pragma unroll
    for (int j = 0; j < 4; ++j) {
        if (base + j < N) tmp[base + j] = run;
        run += c[j];
    }
    if (t == 255) bsum[blockIdx.x] = ssum[255];
}

__global__ __launch_bounds__(256) void scan2_kernel(int* __restrict__ bsum, int nb) {
    __shared__ int sd[256];
    int t = threadIdx.x;
    int v = (t < nb) ? bsum[t] : 0;
    sd[t] = v;
    __syncthreads();
    for (int off = 1; off < 256; off <<= 1) {
        int a = (t >= off) ? sd[t - off] : 0;
        __syncthreads();
        sd[t] += a;
        __syncthreads();
    }
    if (t < nb) bsum[t] = sd[t] - v;
}

__global__ __launch_bounds__(256) void scan3_kernel(const int* __restrict__ tmp,
                                                    const int* __restrict__ bsum,
                                                    int* __restrict__ rowptr,
                                                    int* __restrict__ cursor, int N) {
    int i = blockIdx.x * 256 + threadIdx.x;
    if (i >= N) return;
    int v = tmp[i] + bsum[i >> 10];
    rowptr[i] = v;
    cursor[i] = v;
}

__global__ __launch_bounds__(256) void fill_kernel(const int* __restrict__ ei,
                                                   int* __restrict__ cursor,
                                                   int* __restrict__ srcl, int E) {
    int e = blockIdx.x * 256 + threadIdx.x;
    if (e >= E) return;
    int s = ei[e];
    int d = ei[E + e];
    int pos = atomicAdd(&cursor[d], 1);
    srcl[pos] = s;
}

// gather mean + h = relu(mean + bl + xWr) + global_max_pool (batch sorted)
__global__ __launch_bounds__(128) void gather_pool_kernel(const unsigned short* __restrict__ xPb,
                                                          const int* __restrict__ rowptr,
                                                          const int* __restrict__ rowend,
                                                          const int* __restrict__ srcl,
                                                          const float* __restrict__ bl,
                                                          const int* __restrict__ batch,
                                                          float* __restrict__ gpool, int N) {
    int t = threadIdx.x;
    int n0 = blockIdx.x * NPB;
    if (n0 >= N) return;
    float blv = bl[t];
    float runmax = 0.f;
    int curg = batch[n0];
    int nmax = N - n0; if (nmax > NPB) nmax = NPB;
    for (int i = 0; i < nmax; ++i) {
        int n = n0 + i;
        int gb = batch[n];
        if (gb != curg) {
            atomicMax((unsigned int*)&gpool[curg * HDIM + t], __float_as_uint(runmax));
            runmax = 0.f;
            curg = gb;
        }
        int e0 = rowptr[n];
        int e1 = rowend[n];
        float acc = 0.f;
        for (int e = e0; e < e1; ++e) {
            int s = srcl[e];
            acc += bf2f(xPb[(size_t)s * HO + t]);
        }
        float rv = 1.0f / fmaxf((float)(e1 - e0), 1.0f);
        float h = fmaf(acc, rv, blv + bf2f(xPb[(size_t)n * HO + HDIM + t]));
        h = fmaxf(h, 0.f);
        runmax = fmaxf(runmax, h);
    }
    atomicMax((unsigned int*)&gpool[curg * HDIM + t], __float_as_uint(runmax));
}

__global__ __launch_bounds__(256) void root_kernel(const int* __restrict__ batch,
                                                   int* __restrict__ root, int N) {
    int i = blockIdx.x * 256 + threadIdx.x;
    if (i >= N) return;
    if (i == 0 || batch[i] != batch[i - 1]) root[batch[i]] = i;
}

__global__ __launch_bounds__(128) void final_kernel(const float* __restrict__ x,
                                                    const int* __restrict__ root,
                                                    const float* __restrict__ gpool,
                                                    const float* __restrict__ W0,
                                                    const float* __restrict__ b0,
                                                    const float* __restrict__ W1,
                                                    const float* __restrict__ b1,
                                                    const float* __restrict__ W2,
                                                    const float* __restrict__ b2,
                                                    float* __restrict__ out) {
    __shared__ float xrow[F_IN];
    __shared__ float cat[HO];
    __shared__ float h1s[HDIM];
    __shared__ float part[2][2];
    int g = blockIdx.x, t = threadIdx.x;
    int r = root[g];
    const float* xr = x + (size_t)r * F_IN;
    for (int k = t; k < F_IN; k += HDIM) xrow[k] = xr[k];
    __syncthreads();

    float a = b0[t];
    const float* w0r = W0 + t * F_IN;
    for (int k = 0; k < F_IN; ++k) a = fmaf(xrow[k], w0r[k], a);
    cat[t] = fmaxf(a, 0.f);
    cat[HDIM + t] = gpool[g * HDIM + t];
    __syncthreads();

    float s = b1[t];
    const float* w1r = W1 + t * HO;
    for (int k = 0; k < HO; ++k) s = fmaf(cat[k], w1r[k], s);
    h1s[t] = fmaxf(s, 0.f);
    __syncthreads();

    float hv = h1s[t];
    float p0 = hv * W2[t];
    float p1 = hv * W2[HDIM + t];
#pragma unroll
    for (int o2 = 32; o2 > 0; o2 >>= 1) {
        p0 += __shfl_down(p0, o2);
        p1 += __shfl_down(p1, o2);
    }
    int lane = t & 63, wv = t >> 6;
    if (lane == 0) { part[0][wv] = p0; part[1][wv] = p1; }
    __syncthreads();
    if (t == 0) {
        float z0 = part[0][0] + part[0][1] + b2[0];
        float z1 = part[1][0] + part[1][1] + b2[1];
        float m = fmaxf(z0, z1);
        float lse = m + logf(expf(z0 - m) + expf(z1 - m));
        out[g * CLS + 0] = z0 - lse;
        out[g * CLS + 1] = z1 - lse;
    }
}

extern "C" void kernel_launch(void* const* d_in, const int* in_sizes, int n_in,
                              void* d_out, int out_size, void* d_ws, size_t ws_size,
                              hipStream_t stream) {
    const float* x     = (const float*)d_in[0];
    const int*   ei    = (const int*)d_in[1];
    const int*   batch = (const int*)d_in[2];
    const float* Wl    = (const float*)d_in[3];
    const float* bl    = (const float*)d_in[4];
    const float* Wr    = (const float*)d_in[5];
    const float* W0    = (const float*)d_in[6];
    const float* b0    = (const float*)d_in[7];
    const float* W1    = (const float*)d_in[8];
    const float* b1    = (const float*)d_in[9];
    const float* W2    = (const float*)d_in[10];
    const float* b2    = (const float*)d_in[11];
    float* out = (float*)d_out;

    int N = in_sizes[2];
    int E = in_sizes[1] / 2;
    int G = out_size / CLS;

    char* ws = (char*)d_ws;
    size_t off = 0;
    auto carve = [&](size_t bytes) -> void* {
        void* p = ws + off;
        off += (bytes + 255) & ~(size_t)255;
        return p;
    };
    unsigned short* xPb = (unsigned short*)carve((size_t)N * HO * sizeof(unsigned short));
    char*  zbeg   = ws + off;
    int*   cnt    = (int*)carve((size_t)N * sizeof(int));
    float* gpool  = (float*)carve((size_t)G * HDIM * sizeof(float));
    char*  zend   = ws + off;
    int*   tmp    = (int*)carve((size_t)N * sizeof(int));
    int*   rowptr = (int*)carve((size_t)N * sizeof(int));
    int*   cursor = (int*)carve((size_t)N * sizeof(int));
    int*   srcl   = (int*)carve((size_t)E * sizeof(int));
    int*   bsum   = (int*)carve(1024 * sizeof(int));
    unsigned short* Wb = (unsigned short*)carve((size_t)KP * HO * sizeof(unsigned short));
    int*   root   = (int*)carve((size_t)G * sizeof(int));
    (void)ws_size; (void)n_in;

    int nb = (N + CHUNK - 1) / CHUNK;
    int ntiles = (N + MB - 1) / MB;
    int pblocks = ntiles < PROJ_BLOCKS ? ntiles : PROJ_BLOCKS;

    hipMemsetAsync(zbeg, 0, (size_t)(zend - zbeg), stream);

    prepw_kernel<<<(KP * HO + 255) / 256, 256, 0, stream>>>(Wl, Wr, Wb);
    proj_kernel<<<pblocks, 512, 0, stream>>>(x, Wb, xPb, N, ntiles);

    count_kernel<<<(E + 255) / 256, 256, 0, stream>>>(ei, cnt, E);
    scan1_kernel<<<nb, 256, 0, stream>>>(cnt, tmp, bsum, N);
    scan2_kernel<<<1, 256, 0, stream>>>(bsum, nb);
    scan3_kernel<<<(N + 255) / 256, 256, 0, stream>>>(tmp, bsum, rowptr, cursor, N);
    fill_kernel<<<(E + 255) / 256, 256, 0, stream>>>(ei, cursor, srcl, E);

    gather_pool_kernel<<<(N + NPB - 1) / NPB, HDIM, 0, stream>>>(xPb, rowptr, cursor, srcl,
                                                                 bl, batch, gpool, N);
    root_kernel<<<(N + 255) / 256, 256, 0, stream>>>(batch, root, N);
    final_kernel<<<G, HDIM, 0, stream>>>(x, root, gpool, W0, b0, W1, b1, W2, b2, out);
}